// Round 10
// baseline (226.105 us; speedup 1.0000x reference)
//
#include <hip/hip_runtime.h>
#include <hip/hip_fp16.h>
#include <cmath>

static constexpr int NN = 100000;   // nodes
static constexpr int NE = 1600000;  // edges
static const size_t NW = (size_t)NN * 32;
static constexpr int SUB = 256;         // nodes per sub-slice
static constexpr int NSUB = 391;        // ceil(NN/SUB)
static constexpr int CH = 8192;         // edges per bucket-build chunk
static constexpr int NCH = (NE + CH - 1) / CH;  // 196
static constexpr int BCAP = 5200;       // per-sub-slice bucket cap (mean 4092)
static constexpr int CSRN = NSUB * BCAP; // fixed-stride csr size (2,033,200)
static constexpr int MCAP = 4096;       // masked-node list capacity

// entry: x = src(17b) | fp16(ew)<<17 ; d-plane = dst & 255 (slice-local)
__device__ __forceinline__ float ent_w(unsigned e)
{
    return __half2float(__ushort_as_half((unsigned short)(e >> 17)));
}
__device__ __forceinline__ int ent_s(unsigned e)
{
    int s = (int)(e & 0x1FFFF);
    return s < NN ? s : NN - 1;   // hardened: OOB -> wrong value, not fault
}

__device__ __forceinline__ float4 pack8(const float* v)
{
    union { __half2 h2[4]; float4 f4; } u;
    u.h2[0] = __floats2half2_rn(v[0], v[1]);
    u.h2[1] = __floats2half2_rn(v[2], v[3]);
    u.h2[2] = __floats2half2_rn(v[4], v[5]);
    u.h2[3] = __floats2half2_rn(v[6], v[7]);
    return u.f4;
}

// wave-level inclusive scan (exact, integer) — 64 lanes
__device__ __forceinline__ int wave_incl_scan(int v, int lane)
{
    int s = v;
#pragma unroll
    for (int d = 1; d < 64; d <<= 1) {
        int o = __shfl_up(s, d, 64);
        if (lane >= d) s += o;
    }
    return s;
}

// ---------------------------------------------------------------------------
// fused build+mm1 (R7/R9 structure; ladder scan replaced by wave shfl scan:
// 18 barriers -> 2 in the scatter path).
// ---------------------------------------------------------------------------
__global__ void __launch_bounds__(512) fused_build_mm1_k(
    const int* __restrict__ src, const int* __restrict__ dst,
    const float* __restrict__ ew, const int* __restrict__ curp,
    int* __restrict__ maskb, int* __restrict__ mcount, int* __restrict__ mlist,
    int* __restrict__ bcnt, unsigned* __restrict__ bx,
    unsigned char* __restrict__ bd,
    const float* __restrict__ x, const float* __restrict__ Wrel,
    const float* __restrict__ Wroot, const float* __restrict__ bin,
    __half* __restrict__ proj1, __half* __restrict__ root1)
{
    __shared__ union {
        struct {                        // scatter path: 49,264 B
            unsigned sBufX[CH];         // 32 KB
            unsigned char sBufD[CH];    // 8 KB
            int lhist[NSUB];
            int lpos[NSUB];
            int lstart[NSUB];
            int lbase[NSUB];
            int tscan[512];             // [0..7] wave sums, [8..15] wave offs
        } s;
        struct {                        // mm1 path: 50,688 B (dominates)
            float sX[128 * 65];
            float sW[64 * 68];
        } m;
    } u;

    int t = threadIdx.x;
    int bid = blockIdx.x;

    if (bid < NCH) {
        // ------------------------------ scatter ------------------------------
        for (int i = t; i < NSUB; i += 512) { u.s.lhist[i] = 0; u.s.lpos[i] = 0; }
        __syncthreads();
        int c0 = bid * CH;
        int cur = curp[0];
        unsigned rx[CH / 512];
        int rd[CH / 512];
#pragma unroll
        for (int it = 0; it < CH / 512; ++it) {
            int e = c0 + it * 512 + t;
            rd[it] = -1;
            if (e < NE) {
                int d = dst[e];
                int sv = src[e];
                if ((unsigned)d < (unsigned)NN) {
                    rd[it] = d;
                    unsigned bits = __half_as_ushort(__float2half(ew[e]));
                    rx[it] = ((unsigned)sv & 0x1FFFF) | (bits << 17);
                    atomicAdd(&u.s.lhist[d >> 8], 1);
                    if (sv == cur) {
                        if (atomicExch(maskb + d, 1) == 0) {
                            int idx = atomicAdd(mcount, 1);
                            if (idx < MCAP) mlist[idx] = d;
                        }
                    }
                }
            }
        }
        __syncthreads();
        // wave shfl scan over lhist[512-padded] (2 barriers total)
        {
            int v = (t < NSUB) ? u.s.lhist[t] : 0;
            int lane = t & 63, wv = t >> 6;
            int sI = wave_incl_scan(v, lane);
            if (lane == 63) u.s.tscan[wv] = sI;
            __syncthreads();
            if (t == 0) {
                int r = 0;
#pragma unroll
                for (int w2 = 0; w2 < 8; ++w2) {
                    int xw = u.s.tscan[w2];
                    u.s.tscan[8 + w2] = r;
                    r += xw;
                }
            }
            __syncthreads();
            if (t < NSUB) {
                u.s.lstart[t] = sI + u.s.tscan[8 + wv] - v;
                u.s.lbase[t] = (v > 0) ? atomicAdd(&bcnt[t], v) : 0;
            }
        }
        __syncthreads();
#pragma unroll
        for (int it = 0; it < CH / 512; ++it) {
            if (rd[it] >= 0) {
                int b = rd[it] >> 8;
                int p = atomicAdd(&u.s.lpos[b], 1);
                int pos = u.s.lstart[b] + p;
                u.s.sBufX[pos] = rx[it];
                u.s.sBufD[pos] = (unsigned char)(rd[it] & 255);
            }
        }
        __syncthreads();
        // dump: 16-lane groups, one slice per group round-robin
        int grp = t >> 4, l16 = t & 15;
        for (int b = grp; b < NSUB; b += 32) {
            int s0 = u.s.lstart[b];
            int cb = u.s.lhist[b];
            int gb = u.s.lbase[b];
            size_t gb0 = (size_t)b * BCAP;
            for (int j = l16; j < cb; j += 16) {
                unsigned pos = (unsigned)(gb + j);
                if (pos < (unsigned)BCAP) {
                    bx[gb0 + pos] = u.s.sBufX[s0 + j];
                    bd[gb0 + pos] = u.s.sBufD[s0 + j];
                }
            }
        }
    } else {
        // -------------------------------- mm1 --------------------------------
        int mb = bid - NCH;             // tile of 128 nodes
        for (int i = t; i < 64 * 32; i += 512) {
            int k = i >> 5, j = i & 31;
            u.m.sW[k * 68 + j] = Wrel[i];
            u.m.sW[k * 68 + 32 + j] = Wroot[i];
        }
        int base = mb * 128;
        for (int i = t; i < 2048; i += 512) {
            int node = i >> 4;
            int k = (i & 15) * 4;
            int n = base + node;
            if (n >= NN) n = NN - 1;
            float4 v4 = *(const float4*)(x + (size_t)n * 64 + k);
            float* p = u.m.sX + node * 65 + k;
            p[0] = v4.x; p[1] = v4.y; p[2] = v4.z; p[3] = v4.w;
        }
        __syncthreads();
        int cg = t & 7;                 // 8 col-groups x 8 cols = 64 outputs
        int ng = t >> 3;                // 64 node-groups x 2 nodes = 128
        int c0m = 8 * cg;
        float acc[2][8] = {};
        for (int k = 0; k < 64; ++k) {
            float xv0 = u.m.sX[(2 * ng + 0) * 65 + k];
            float xv1 = u.m.sX[(2 * ng + 1) * 65 + k];
            float4 w0 = *(const float4*)(u.m.sW + k * 68 + c0m);
            float4 w1 = *(const float4*)(u.m.sW + k * 68 + c0m + 4);
            const float* wp = (const float*)&w0;
#pragma unroll
            for (int j = 0; j < 4; ++j) {
                float w = wp[j];
                acc[0][j] = fmaf(xv0, w, acc[0][j]);
                acc[1][j] = fmaf(xv1, w, acc[1][j]);
            }
            const float* wq = (const float*)&w1;
#pragma unroll
            for (int j = 0; j < 4; ++j) {
                float w = wq[j];
                acc[0][4 + j] = fmaf(xv0, w, acc[0][4 + j]);
                acc[1][4 + j] = fmaf(xv1, w, acc[1][4 + j]);
            }
        }
#pragma unroll
        for (int r = 0; r < 2; ++r) {
            int n = base + 2 * ng + r;
            if (n >= NN) break;
            if (cg < 4) {
                *(float4*)(proj1 + (size_t)n * 32 + c0m) = pack8(acc[r]);
            } else {
                int c = c0m - 32;
                float vv[8];
#pragma unroll
                for (int j = 0; j < 8; ++j) vv[j] = acc[r][j] + bin[c + j];
                *(float4*)(root1 + (size_t)n * 32 + c) = pack8(vv);
            }
        }
    }
}

// ---------------------------------------------------------------------------
// sortagg1 (R7 structure; ladder scan replaced by wave shfl scan: 16 barriers
// -> 2). One block per sub-slice, 1024 threads. Sorted entries stay in LDS
// for the gather; csr4/deg/off dumped for agg2 + masked_softmax; h rounds
// through global fp16 h1.
// ---------------------------------------------------------------------------
__global__ void __launch_bounds__(1024) sortagg1_k(
    const unsigned* __restrict__ bx, const unsigned char* __restrict__ bd,
    const int* __restrict__ bcnt,
    const __half* __restrict__ proj1, const __half* __restrict__ root1,
    unsigned* __restrict__ csr4, int* __restrict__ deg, int* __restrict__ off,
    __half* __restrict__ h1)
{
    __shared__ unsigned sX[BCAP];        // 20.8 KB (staging)
    __shared__ unsigned char sD[BCAP];   // 5.2 KB
    __shared__ unsigned sE[BCAP];        // 20.8 KB (sorted entries)
    __shared__ int lhist[SUB];
    __shared__ int lstart[SUB];
    __shared__ int lcur[SUB];
    __shared__ int tscan[16];            // [0..3] wave sums, [8..11] offs
    int g = blockIdx.x, t = threadIdx.x;
    if (t < SUB) { lhist[t] = 0; lcur[t] = 0; }
    __syncthreads();
    int cnt = bcnt[g];
    if (cnt < 0) cnt = 0;
    if (cnt > BCAP) cnt = BCAP;
    size_t gbase = (size_t)g * BCAP;
    for (int i = t; i < cnt; i += 1024) {
        unsigned e = bx[gbase + i];
        unsigned char d = bd[gbase + i];
        sX[i] = e;
        sD[i] = d;
        atomicAdd(&lhist[d], 1);
    }
    __syncthreads();
    // wave shfl scan over lhist[256] (2 barriers)
    {
        int v = (t < SUB) ? lhist[t] : 0;
        int lane = t & 63, wv = t >> 6;
        int sI = wave_incl_scan(v, lane);
        if (t < SUB && lane == 63) tscan[wv] = sI;
        __syncthreads();
        if (t == 0) {
            int r = 0;
#pragma unroll
            for (int w2 = 0; w2 < 4; ++w2) {
                int xw = tscan[w2];
                tscan[8 + w2] = r;
                r += xw;
            }
        }
        __syncthreads();
        if (t < SUB) lstart[t] = sI + tscan[8 + wv] - v;
    }
    __syncthreads();
    for (int i = t; i < cnt; i += 1024) {
        int ld = (int)sD[i];
        int p = atomicAdd(&lcur[ld], 1);
        int pos = lstart[ld] + p;
        if ((unsigned)pos < (unsigned)BCAP) sE[pos] = sX[i];
    }
    __syncthreads();
    int base = g * BCAP;
    // dump for agg2 / masked_softmax (coalesced)
    if (t < SUB) {
        int n = g * SUB + t;
        if (n < NN) {
            deg[n] = lhist[t];
            off[n] = base + lstart[t];
        }
    }
    for (int i = t; i < cnt; i += 1024) {
        unsigned pos = (unsigned)(base + i);
        if (pos < (unsigned)CSRN) csr4[pos] = sE[i];
    }
    // ----------------------------- gather phase -----------------------------
    int q = t & 3;
    int f0 = q * 8;
    int l = t >> 2;                 // local node 0..255
    int n = g * SUB + l;
    if (n >= NN) return;
    int st = lstart[l];
    int dg = lhist[l];
    if (st < 0) st = 0;
    if (st > BCAP) st = BCAP;
    if (dg < 0) dg = 0;
    if (dg > BCAP - st) dg = BCAP - st;
    float acc[8] = {0.f, 0.f, 0.f, 0.f, 0.f, 0.f, 0.f, 0.f};
    int i = 0;
    for (; i + 1 < dg; i += 2) {
        unsigned e0 = sE[st + i];
        unsigned e1 = sE[st + i + 1];
        float w0 = ent_w(e0), w1 = ent_w(e1);
        float4 r0 = *(const float4*)(proj1 + (size_t)ent_s(e0) * 32 + f0);
        float4 r1 = *(const float4*)(proj1 + (size_t)ent_s(e1) * 32 + f0);
        const __half2* h0 = (const __half2*)&r0;
        const __half2* h1p = (const __half2*)&r1;
#pragma unroll
        for (int u = 0; u < 4; ++u) {
            float2 a = __half22float2(h0[u]);
            float2 b = __half22float2(h1p[u]);
            acc[2 * u] = fmaf(w0, a.x, acc[2 * u]);
            acc[2 * u + 1] = fmaf(w0, a.y, acc[2 * u + 1]);
            acc[2 * u] = fmaf(w1, b.x, acc[2 * u]);
            acc[2 * u + 1] = fmaf(w1, b.y, acc[2 * u + 1]);
        }
    }
    if (i < dg) {
        unsigned e0 = sE[st + i];
        float w0 = ent_w(e0);
        float4 r0 = *(const float4*)(proj1 + (size_t)ent_s(e0) * 32 + f0);
        const __half2* h0 = (const __half2*)&r0;
#pragma unroll
        for (int u = 0; u < 4; ++u) {
            float2 a = __half22float2(h0[u]);
            acc[2 * u] = fmaf(w0, a.x, acc[2 * u]);
            acc[2 * u + 1] = fmaf(w0, a.y, acc[2 * u + 1]);
        }
    }
    float4 rr = *(const float4*)(root1 + (size_t)n * 32 + f0);
    const __half2* rp = (const __half2*)&rr;
    float h[8];
#pragma unroll
    for (int u = 0; u < 4; ++u) {
        float2 f2 = __half22float2(rp[u]);
        h[2 * u] = fmaxf(acc[2 * u] + f2.x, 0.f);
        h[2 * u + 1] = fmaxf(acc[2 * u + 1] + f2.y, 0.f);
    }
    *(float4*)(h1 + (size_t)n * 32 + f0) = pack8(h);
}

// ---------------------------------------------------------------------------
// mm2: proj2 = fp16(h1@Wh_rel), root2 = fp16(h1@Wh_root + bh). K=32.
// ---------------------------------------------------------------------------
__global__ void __launch_bounds__(256) mm2_k(
    const __half* __restrict__ h1, const float* __restrict__ Wrel,
    const float* __restrict__ Wroot, const float* __restrict__ bh,
    __half* __restrict__ proj2, __half* __restrict__ root2)
{
    __shared__ float sX[128 * 33];
    __shared__ float sW[32 * 68];
    int t = threadIdx.x;
    for (int i = t; i < 32 * 32; i += 256) {
        int k = i >> 5, j = i & 31;
        sW[k * 68 + j] = Wrel[i];
        sW[k * 68 + 32 + j] = Wroot[i];
    }
    int base = blockIdx.x * 128;
    for (int i = t; i < 512; i += 256) {
        int node = i >> 2;
        int hs = (i & 3) * 8;
        int n = base + node;
        if (n >= NN) n = NN - 1;
        float4 v = *(const float4*)(h1 + (size_t)n * 32 + hs);
        const __half2* hp = (const __half2*)&v;
        float* p = sX + node * 33 + hs;
#pragma unroll
        for (int u = 0; u < 4; ++u) {
            float2 f2 = __half22float2(hp[u]);
            p[2 * u] = f2.x;
            p[2 * u + 1] = f2.y;
        }
    }
    __syncthreads();
    int cg = t & 7;
    int ng = t >> 3;
    int c0 = 8 * cg;
    float acc[4][8] = {};
    for (int k = 0; k < 32; ++k) {
        float xv0 = sX[(4 * ng + 0) * 33 + k];
        float xv1 = sX[(4 * ng + 1) * 33 + k];
        float xv2 = sX[(4 * ng + 2) * 33 + k];
        float xv3 = sX[(4 * ng + 3) * 33 + k];
        float4 w0 = *(const float4*)(sW + k * 68 + c0);
        float4 w1 = *(const float4*)(sW + k * 68 + c0 + 4);
        const float* wp = (const float*)&w0;
#pragma unroll
        for (int j = 0; j < 4; ++j) {
            float w = wp[j];
            acc[0][j] = fmaf(xv0, w, acc[0][j]);
            acc[1][j] = fmaf(xv1, w, acc[1][j]);
            acc[2][j] = fmaf(xv2, w, acc[2][j]);
            acc[3][j] = fmaf(xv3, w, acc[3][j]);
        }
        const float* wq = (const float*)&w1;
#pragma unroll
        for (int j = 0; j < 4; ++j) {
            float w = wq[j];
            acc[0][4 + j] = fmaf(xv0, w, acc[0][4 + j]);
            acc[1][4 + j] = fmaf(xv1, w, acc[1][4 + j]);
            acc[2][4 + j] = fmaf(xv2, w, acc[2][4 + j]);
            acc[3][4 + j] = fmaf(xv3, w, acc[3][4 + j]);
        }
    }
#pragma unroll
    for (int r = 0; r < 4; ++r) {
        int n = base + 4 * ng + r;
        if (n >= NN) break;
        if (cg < 4) {
            *(float4*)(proj2 + (size_t)n * 32 + c0) = pack8(acc[r]);
        } else {
            int c = c0 - 32;
            float v[8];
#pragma unroll
            for (int j = 0; j < 8; ++j) v[j] = acc[r][j] + bh[c + j];
            *(float4*)(root2 + (size_t)n * 32 + c) = pack8(v);
        }
    }
}

// ---------------------------------------------------------------------------
// agg2: 4-deep gather; epilogue computes the 4 OUT=1 head dots.
// Also zeroes out_p/out_v.
// ---------------------------------------------------------------------------
__global__ void __launch_bounds__(256) agg2_v4(
    const __half* __restrict__ proj2, const __half* __restrict__ root2,
    const float* __restrict__ Wp_rel, const float* __restrict__ Wp_root,
    const float* __restrict__ bp, const float* __restrict__ Wv_rel,
    const float* __restrict__ Wv_root, const float* __restrict__ bv,
    const unsigned* __restrict__ csr4, const int* __restrict__ off,
    const int* __restrict__ deg, float2* __restrict__ pv,
    float* __restrict__ pbase, float* __restrict__ vbase,
    float* __restrict__ out_p, float* __restrict__ out_v)
{
    __shared__ float sHead[4 * 32];
    if (threadIdx.x < 32) {
        sHead[threadIdx.x] = Wp_rel[threadIdx.x];
        sHead[32 + threadIdx.x] = Wp_root[threadIdx.x];
        sHead[64 + threadIdx.x] = Wv_rel[threadIdx.x];
        sHead[96 + threadIdx.x] = Wv_root[threadIdx.x];
    }
    __syncthreads();
    int t = threadIdx.x;
    int q = t & 3;
    int f0 = q * 8;
    int n = blockIdx.x * 64 + (t >> 2);
    if (n >= NN) return;
    int st = off[n];
    int dg = deg[n];
    if (st < 0) st = 0;
    if (st > CSRN) st = CSRN;
    if (dg < 0) dg = 0;
    if (dg > CSRN - st) dg = CSRN - st;
    float acc[8] = {0.f, 0.f, 0.f, 0.f, 0.f, 0.f, 0.f, 0.f};
    int i = 0;
    for (; i + 3 < dg; i += 4) {
        unsigned e0 = csr4[st + i];
        unsigned e1 = csr4[st + i + 1];
        unsigned e2 = csr4[st + i + 2];
        unsigned e3 = csr4[st + i + 3];
        float4 r0 = *(const float4*)(proj2 + (size_t)ent_s(e0) * 32 + f0);
        float4 r1 = *(const float4*)(proj2 + (size_t)ent_s(e1) * 32 + f0);
        float4 r2 = *(const float4*)(proj2 + (size_t)ent_s(e2) * 32 + f0);
        float4 r3 = *(const float4*)(proj2 + (size_t)ent_s(e3) * 32 + f0);
        float w0 = ent_w(e0), w1 = ent_w(e1), w2 = ent_w(e2), w3 = ent_w(e3);
        const __half2* h0 = (const __half2*)&r0;
        const __half2* h1p = (const __half2*)&r1;
        const __half2* h2p = (const __half2*)&r2;
        const __half2* h3p = (const __half2*)&r3;
#pragma unroll
        for (int u = 0; u < 4; ++u) {
            float2 a = __half22float2(h0[u]);
            float2 b = __half22float2(h1p[u]);
            float2 c = __half22float2(h2p[u]);
            float2 d = __half22float2(h3p[u]);
            acc[2 * u]     = fmaf(w0, a.x, acc[2 * u]);
            acc[2 * u + 1] = fmaf(w0, a.y, acc[2 * u + 1]);
            acc[2 * u]     = fmaf(w1, b.x, acc[2 * u]);
            acc[2 * u + 1] = fmaf(w1, b.y, acc[2 * u + 1]);
            acc[2 * u]     = fmaf(w2, c.x, acc[2 * u]);
            acc[2 * u + 1] = fmaf(w2, c.y, acc[2 * u + 1]);
            acc[2 * u]     = fmaf(w3, d.x, acc[2 * u]);
            acc[2 * u + 1] = fmaf(w3, d.y, acc[2 * u + 1]);
        }
    }
    for (; i < dg; ++i) {
        unsigned e0 = csr4[st + i];
        float w0 = ent_w(e0);
        float4 r0 = *(const float4*)(proj2 + (size_t)ent_s(e0) * 32 + f0);
        const __half2* h0 = (const __half2*)&r0;
#pragma unroll
        for (int u = 0; u < 4; ++u) {
            float2 a = __half22float2(h0[u]);
            acc[2 * u] = fmaf(w0, a.x, acc[2 * u]);
            acc[2 * u + 1] = fmaf(w0, a.y, acc[2 * u + 1]);
        }
    }
    float4 rr = *(const float4*)(root2 + (size_t)n * 32 + f0);
    const __half2* rp = (const __half2*)&rr;
    float h[8];
#pragma unroll
    for (int u = 0; u < 4; ++u) {
        float2 f2 = __half22float2(rp[u]);
        h[2 * u] = fmaxf(acc[2 * u] + f2.x, 0.f);
        h[2 * u + 1] = fmaxf(acc[2 * u + 1] + f2.y, 0.f);
    }
    float prv = 0.f, pov = 0.f, vrv = 0.f, vov = 0.f;
#pragma unroll
    for (int j = 0; j < 8; ++j) {
        prv = fmaf(h[j], sHead[f0 + j], prv);
        pov = fmaf(h[j], sHead[32 + f0 + j], pov);
        vrv = fmaf(h[j], sHead[64 + f0 + j], vrv);
        vov = fmaf(h[j], sHead[96 + f0 + j], vov);
    }
#pragma unroll
    for (int m = 1; m <= 2; m <<= 1) {
        prv += __shfl_xor(prv, m, 64);
        pov += __shfl_xor(pov, m, 64);
        vrv += __shfl_xor(vrv, m, 64);
        vov += __shfl_xor(vov, m, 64);
    }
    if (q == 0) {
        pv[n] = make_float2(prv, vrv);
        pbase[n] = pov + bp[0];
        vbase[n] = vov + bv[0];
        out_p[n] = 0.f;
        out_v[n] = 0.f;
    }
}

// ---------------------------------------------------------------------------
// Single-block masked softmax; 4 lanes per node cut the serial pv-gather
// chain 4x (2-step shfl reduce). Sparse writes.
// ---------------------------------------------------------------------------
__global__ void __launch_bounds__(256) masked_softmax_k(
    const int* __restrict__ mlist, const int* __restrict__ mcount,
    const unsigned* __restrict__ csr4, const int* __restrict__ off,
    const int* __restrict__ deg, const float2* __restrict__ pv,
    const float* __restrict__ pbase, const float* __restrict__ vbase,
    float* __restrict__ out_p, float* __restrict__ out_v)
{
    __shared__ float sPm[MCAP];
    __shared__ float sV[MCAP];
    __shared__ int sN[MCAP];
    __shared__ float sMx, sSum;
    __shared__ float sred[4];
    int m = mcount[0];
    if (m > MCAP) m = MCAP;
    if (m < 0) m = 0;
    int lane4 = threadIdx.x & 3;
    for (int idx = threadIdx.x >> 2; idx < m; idx += 64) {
        int n = mlist[idx];
        if ((unsigned)n >= (unsigned)NN) n = 0;
        int st = off[n];
        int dg = deg[n];
        if (st < 0) st = 0;
        if (st > CSRN) st = CSRN;
        if (dg < 0) dg = 0;
        if (dg > CSRN - st) dg = CSRN - st;
        float pa = 0.f, va = 0.f;
        for (int i = lane4; i < dg; i += 4) {
            unsigned ent = csr4[st + i];
            int s = ent_s(ent);
            float w = ent_w(ent);
            float2 tv = pv[s];
            pa = fmaf(tv.x, w, pa);
            va = fmaf(tv.y, w, va);
        }
        pa += __shfl_xor(pa, 1, 64);
        pa += __shfl_xor(pa, 2, 64);
        va += __shfl_xor(va, 1, 64);
        va += __shfl_xor(va, 2, 64);
        if (lane4 == 0) {
            sN[idx] = n;
            float p = pa + pbase[n];
            sPm[idx] = (p == 0.f) ? -INFINITY : p;
            sV[idx] = va + vbase[n];
        }
    }
    __syncthreads();
    float mx = -INFINITY;
    for (int i = threadIdx.x; i < m; i += 256) mx = fmaxf(mx, sPm[i]);
#pragma unroll
    for (int k = 32; k; k >>= 1) mx = fmaxf(mx, __shfl_xor(mx, k, 64));
    if ((threadIdx.x & 63) == 0) sred[threadIdx.x >> 6] = mx;
    __syncthreads();
    if (threadIdx.x == 0)
        sMx = fmaxf(fmaxf(sred[0], sred[1]), fmaxf(sred[2], sred[3]));
    __syncthreads();
    float sum = 0.f;
    for (int i = threadIdx.x; i < m; i += 256) {
        float x = sPm[i];
        sum += (x == -INFINITY) ? 0.f : expf(x - sMx);
    }
#pragma unroll
    for (int k = 32; k; k >>= 1) sum += __shfl_xor(sum, k, 64);
    if ((threadIdx.x & 63) == 0) sred[threadIdx.x >> 6] = sum;
    __syncthreads();
    if (threadIdx.x == 0) sSum = sred[0] + sred[1] + sred[2] + sred[3];
    __syncthreads();
    for (int idx = threadIdx.x; idx < m; idx += 256) {
        int n = sN[idx];
        float x = sPm[idx];
        out_p[n] = (x == -INFINITY) ? 0.f : expf(x - sMx) / sSum;
        out_v[n] = sV[idx];
    }
}

// ---------------------------------------------------------------------------
extern "C" void kernel_launch(void* const* d_in, const int* in_sizes, int n_in,
                              void* d_out, int out_size, void* d_ws,
                              size_t ws_size, hipStream_t stream)
{
    const float* x        = (const float*)d_in[0];
    const int*   ei       = (const int*)d_in[1];
    const float* ew       = (const float*)d_in[2];
    const int*   cur      = (const int*)d_in[3];
    const float* Win_rel  = (const float*)d_in[4];
    const float* bin_rel  = (const float*)d_in[5];
    const float* Win_root = (const float*)d_in[6];
    const float* Wh_rel   = (const float*)d_in[7];
    const float* bh_rel   = (const float*)d_in[8];
    const float* Wh_root  = (const float*)d_in[9];
    const float* Wp_rel   = (const float*)d_in[10];
    const float* bp       = (const float*)d_in[11];
    const float* Wp_root  = (const float*)d_in[12];
    const float* Wv_rel   = (const float*)d_in[13];
    const float* bv       = (const float*)d_in[14];
    const float* Wv_root  = (const float*)d_in[15];

    const int* srcA = ei;
    const int* dstA = ei + NE;

    // Workspace (~53 MB):
    //   csr4 (8.13MB) | deg | off | [zeroed: maskb | mcount | bcnt] | mlist |
    //   proj1 root1 h1 proj2 root2 (32MB) | pv/pbase/vbase |
    //   bucket_x (8.13MB) | bucket_d (2.03MB)
    char* w8 = (char*)d_ws;
    unsigned* csr4 = (unsigned*)w8;          // CSRN u32
    int* deg    = (int*)(csr4 + CSRN);       // NN
    int* off    = deg + NN;                  // NN
    int* maskb  = off + NN;                  // NN }  zeroed
    int* mcount = maskb + NN;                // 8  }
    int* bcnt   = mcount + 8;                // 400 } (NN+8+400 ints)
    int* mlist  = bcnt + 400;                // MCAP
    __half* proj1 = (__half*)(mlist + MCAP);
    __half* root1 = proj1 + NW;
    __half* h1    = root1 + NW;
    __half* proj2 = h1 + NW;
    __half* root2 = proj2 + NW;
    float2* pv    = (float2*)(root2 + NW);   // 800 KB
    float* pbase  = (float*)(pv + NN);       // 400 KB
    float* vbase  = pbase + NN;              // 400 KB
    unsigned* bucket_x = (unsigned*)(vbase + NN);                // CSRN u32
    unsigned char* bucket_d = (unsigned char*)(bucket_x + CSRN); // CSRN u8

    float* out_p = (float*)d_out;
    float* out_v = out_p + NN;

    const int NB_MM    = (NN + 127) / 128;   // 782
    const int NB_AGG   = (NN + 63) / 64;     // 1563
    const int NB_FUSED = NCH + NB_MM;        // 978

    // single memset: maskb + mcount + bcnt
    hipMemsetAsync(maskb, 0, ((size_t)NN + 8 + 400) * sizeof(int), stream);

    // --- fused CSR-bucket build (split planes, atomic reservation) + mm1 ---
    fused_build_mm1_k<<<NB_FUSED, 512, 0, stream>>>(
        srcA, dstA, ew, cur, maskb, mcount, mlist, bcnt, bucket_x, bucket_d,
        x, Win_rel, Win_root, bin_rel, proj1, root1);
    // --- per-sub-slice sort (in-LDS) + agg1 fused; dumps csr/deg/off ---
    sortagg1_k<<<NSUB, 1024, 0, stream>>>(bucket_x, bucket_d, bcnt,
                                          proj1, root1, csr4, deg, off, h1);
    // --- layer chain ---
    mm2_k<<<NB_MM, 256, 0, stream>>>(h1, Wh_rel, Wh_root, bh_rel, proj2, root2);
    agg2_v4<<<NB_AGG, 256, 0, stream>>>(proj2, root2, Wp_rel, Wp_root, bp,
                                        Wv_rel, Wv_root, bv, csr4, off, deg,
                                        pv, pbase, vbase, out_p, out_v);
    // --- masked softmax (sparse outputs) ---
    masked_softmax_k<<<1, 256, 0, stream>>>(mlist, mcount, csr4, off, deg, pv,
                                            pbase, vbase, out_p, out_v);
}

// Round 11
// 214.913 us; speedup vs baseline: 1.0521x; 1.0521x over previous
//
#include <hip/hip_runtime.h>
#include <hip/hip_fp16.h>
#include <cmath>

static constexpr int NN = 100000;   // nodes
static constexpr int NE = 1600000;  // edges
static const size_t NW = (size_t)NN * 32;
static constexpr int SUB = 256;         // nodes per sub-slice
static constexpr int NSUB = 391;        // ceil(NN/SUB)
static constexpr int CH = 8192;         // edges per bucket-build chunk
static constexpr int NCH = (NE + CH - 1) / CH;  // 196
static constexpr int BCAP = 5200;       // per-sub-slice bucket cap (mean 4092)
static constexpr int CSRN = NSUB * BCAP; // fixed-stride csr size (2,033,200)
static constexpr int MCAP = 4096;       // masked-node list capacity
static constexpr int NCAP = 8192;       // needlist capacity (sources of masked
                                        // in-edges ~1.3K expected; 6x margin)

// entry: x = src(17b) | fp16(ew)<<17 ; d-plane = dst & 255 (slice-local)
__device__ __forceinline__ float ent_w(unsigned e)
{
    return __half2float(__ushort_as_half((unsigned short)(e >> 17)));
}
__device__ __forceinline__ int ent_s(unsigned e)
{
    int s = (int)(e & 0x1FFFF);
    return s < NN ? s : NN - 1;   // hardened: OOB -> wrong value, not fault
}

__device__ __forceinline__ float4 pack8(const float* v)
{
    union { __half2 h2[4]; float4 f4; } u;
    u.h2[0] = __floats2half2_rn(v[0], v[1]);
    u.h2[1] = __floats2half2_rn(v[2], v[3]);
    u.h2[2] = __floats2half2_rn(v[4], v[5]);
    u.h2[3] = __floats2half2_rn(v[6], v[7]);
    return u.f4;
}

// wave-level inclusive scan (exact, integer) — 64 lanes
__device__ __forceinline__ int wave_incl_scan(int v, int lane)
{
    int s = v;
#pragma unroll
    for (int d = 1; d < 64; d <<= 1) {
        int o = __shfl_up(s, d, 64);
        if (lane >= d) s += o;
    }
    return s;
}

// ---------------------------------------------------------------------------
// fused build+mm1 (UNCHANGED from verified R9/R10 configuration).
// ---------------------------------------------------------------------------
__global__ void __launch_bounds__(512) fused_build_mm1_k(
    const int* __restrict__ src, const int* __restrict__ dst,
    const float* __restrict__ ew, const int* __restrict__ curp,
    int* __restrict__ maskb, int* __restrict__ mcount, int* __restrict__ mlist,
    int* __restrict__ bcnt, unsigned* __restrict__ bx,
    unsigned char* __restrict__ bd,
    const float* __restrict__ x, const float* __restrict__ Wrel,
    const float* __restrict__ Wroot, const float* __restrict__ bin,
    __half* __restrict__ proj1, __half* __restrict__ root1)
{
    __shared__ union {
        struct {                        // scatter path: 49,264 B
            unsigned sBufX[CH];         // 32 KB
            unsigned char sBufD[CH];    // 8 KB
            int lhist[NSUB];
            int lpos[NSUB];
            int lstart[NSUB];
            int lbase[NSUB];
            int tscan[512];             // [0..7] wave sums, [8..15] wave offs
        } s;
        struct {                        // mm1 path: 50,688 B (dominates)
            float sX[128 * 65];
            float sW[64 * 68];
        } m;
    } u;

    int t = threadIdx.x;
    int bid = blockIdx.x;

    if (bid < NCH) {
        // ------------------------------ scatter ------------------------------
        for (int i = t; i < NSUB; i += 512) { u.s.lhist[i] = 0; u.s.lpos[i] = 0; }
        __syncthreads();
        int c0 = bid * CH;
        int cur = curp[0];
        unsigned rx[CH / 512];
        int rd[CH / 512];
#pragma unroll
        for (int it = 0; it < CH / 512; ++it) {
            int e = c0 + it * 512 + t;
            rd[it] = -1;
            if (e < NE) {
                int d = dst[e];
                int sv = src[e];
                if ((unsigned)d < (unsigned)NN) {
                    rd[it] = d;
                    unsigned bits = __half_as_ushort(__float2half(ew[e]));
                    rx[it] = ((unsigned)sv & 0x1FFFF) | (bits << 17);
                    atomicAdd(&u.s.lhist[d >> 8], 1);
                    if (sv == cur) {
                        if (atomicExch(maskb + d, 1) == 0) {
                            int idx = atomicAdd(mcount, 1);
                            if (idx < MCAP) mlist[idx] = d;
                        }
                    }
                }
            }
        }
        __syncthreads();
        // wave shfl scan over lhist (2 barriers total)
        {
            int v = (t < NSUB) ? u.s.lhist[t] : 0;
            int lane = t & 63, wv = t >> 6;
            int sI = wave_incl_scan(v, lane);
            if (lane == 63) u.s.tscan[wv] = sI;
            __syncthreads();
            if (t == 0) {
                int r = 0;
#pragma unroll
                for (int w2 = 0; w2 < 8; ++w2) {
                    int xw = u.s.tscan[w2];
                    u.s.tscan[8 + w2] = r;
                    r += xw;
                }
            }
            __syncthreads();
            if (t < NSUB) {
                u.s.lstart[t] = sI + u.s.tscan[8 + wv] - v;
                u.s.lbase[t] = (v > 0) ? atomicAdd(&bcnt[t], v) : 0;
            }
        }
        __syncthreads();
#pragma unroll
        for (int it = 0; it < CH / 512; ++it) {
            if (rd[it] >= 0) {
                int b = rd[it] >> 8;
                int p = atomicAdd(&u.s.lpos[b], 1);
                int pos = u.s.lstart[b] + p;
                u.s.sBufX[pos] = rx[it];
                u.s.sBufD[pos] = (unsigned char)(rd[it] & 255);
            }
        }
        __syncthreads();
        // dump: 16-lane groups, one slice per group round-robin
        int grp = t >> 4, l16 = t & 15;
        for (int b = grp; b < NSUB; b += 32) {
            int s0 = u.s.lstart[b];
            int cb = u.s.lhist[b];
            int gb = u.s.lbase[b];
            size_t gb0 = (size_t)b * BCAP;
            for (int j = l16; j < cb; j += 16) {
                unsigned pos = (unsigned)(gb + j);
                if (pos < (unsigned)BCAP) {
                    bx[gb0 + pos] = u.s.sBufX[s0 + j];
                    bd[gb0 + pos] = u.s.sBufD[s0 + j];
                }
            }
        }
    } else {
        // -------------------------------- mm1 --------------------------------
        int mb = bid - NCH;             // tile of 128 nodes
        for (int i = t; i < 64 * 32; i += 512) {
            int k = i >> 5, j = i & 31;
            u.m.sW[k * 68 + j] = Wrel[i];
            u.m.sW[k * 68 + 32 + j] = Wroot[i];
        }
        int base = mb * 128;
        for (int i = t; i < 2048; i += 512) {
            int node = i >> 4;
            int k = (i & 15) * 4;
            int n = base + node;
            if (n >= NN) n = NN - 1;
            float4 v4 = *(const float4*)(x + (size_t)n * 64 + k);
            float* p = u.m.sX + node * 65 + k;
            p[0] = v4.x; p[1] = v4.y; p[2] = v4.z; p[3] = v4.w;
        }
        __syncthreads();
        int cg = t & 7;                 // 8 col-groups x 8 cols = 64 outputs
        int ng = t >> 3;                // 64 node-groups x 2 nodes = 128
        int c0m = 8 * cg;
        float acc[2][8] = {};
        for (int k = 0; k < 64; ++k) {
            float xv0 = u.m.sX[(2 * ng + 0) * 65 + k];
            float xv1 = u.m.sX[(2 * ng + 1) * 65 + k];
            float4 w0 = *(const float4*)(u.m.sW + k * 68 + c0m);
            float4 w1 = *(const float4*)(u.m.sW + k * 68 + c0m + 4);
            const float* wp = (const float*)&w0;
#pragma unroll
            for (int j = 0; j < 4; ++j) {
                float w = wp[j];
                acc[0][j] = fmaf(xv0, w, acc[0][j]);
                acc[1][j] = fmaf(xv1, w, acc[1][j]);
            }
            const float* wq = (const float*)&w1;
#pragma unroll
            for (int j = 0; j < 4; ++j) {
                float w = wq[j];
                acc[0][4 + j] = fmaf(xv0, w, acc[0][4 + j]);
                acc[1][4 + j] = fmaf(xv1, w, acc[1][4 + j]);
            }
        }
#pragma unroll
        for (int r = 0; r < 2; ++r) {
            int n = base + 2 * ng + r;
            if (n >= NN) break;
            if (cg < 4) {
                *(float4*)(proj1 + (size_t)n * 32 + c0m) = pack8(acc[r]);
            } else {
                int c = c0m - 32;
                float vv[8];
#pragma unroll
                for (int j = 0; j < 8; ++j) vv[j] = acc[r][j] + bin[c + j];
                *(float4*)(root1 + (size_t)n * 32 + c) = pack8(vv);
            }
        }
    }
}

// ---------------------------------------------------------------------------
// sortagg1 (R10 structure + needlist marking): one block per sub-slice,
// 1024 threads. LDS counting sort; sorted entries stay in LDS for the gather;
// csr4/deg/off dumped for softmax/needgather. NEW: for masked nodes in this
// slice, append the node + its in-edge sources to the deduped needlist —
// these are the ONLY nodes whose layer-2 output is ever read.
// ---------------------------------------------------------------------------
__global__ void __launch_bounds__(1024) sortagg1_k(
    const unsigned* __restrict__ bx, const unsigned char* __restrict__ bd,
    const int* __restrict__ bcnt, const int* __restrict__ maskb,
    int* __restrict__ needb, int* __restrict__ ncount,
    int* __restrict__ needlist,
    const __half* __restrict__ proj1, const __half* __restrict__ root1,
    unsigned* __restrict__ csr4, int* __restrict__ deg, int* __restrict__ off,
    __half* __restrict__ h1)
{
    __shared__ unsigned sX[BCAP];        // 20.8 KB (staging)
    __shared__ unsigned char sD[BCAP];   // 5.2 KB
    __shared__ unsigned sE[BCAP];        // 20.8 KB (sorted entries)
    __shared__ int lhist[SUB];
    __shared__ int lstart[SUB];
    __shared__ int lcur[SUB];
    __shared__ int tscan[16];            // [0..3] wave sums, [8..11] offs
    int g = blockIdx.x, t = threadIdx.x;
    if (t < SUB) { lhist[t] = 0; lcur[t] = 0; }
    __syncthreads();
    int cnt = bcnt[g];
    if (cnt < 0) cnt = 0;
    if (cnt > BCAP) cnt = BCAP;
    size_t gbase = (size_t)g * BCAP;
    for (int i = t; i < cnt; i += 1024) {
        unsigned e = bx[gbase + i];
        unsigned char d = bd[gbase + i];
        sX[i] = e;
        sD[i] = d;
        atomicAdd(&lhist[d], 1);
    }
    __syncthreads();
    // wave shfl scan over lhist[256] (2 barriers)
    {
        int v = (t < SUB) ? lhist[t] : 0;
        int lane = t & 63, wv = t >> 6;
        int sI = wave_incl_scan(v, lane);
        if (t < SUB && lane == 63) tscan[wv] = sI;
        __syncthreads();
        if (t == 0) {
            int r = 0;
#pragma unroll
            for (int w2 = 0; w2 < 4; ++w2) {
                int xw = tscan[w2];
                tscan[8 + w2] = r;
                r += xw;
            }
        }
        __syncthreads();
        if (t < SUB) lstart[t] = sI + tscan[8 + wv] - v;
    }
    __syncthreads();
    for (int i = t; i < cnt; i += 1024) {
        int ld = (int)sD[i];
        int p = atomicAdd(&lcur[ld], 1);
        int pos = lstart[ld] + p;
        if ((unsigned)pos < (unsigned)BCAP) sE[pos] = sX[i];
    }
    __syncthreads();
    int base = g * BCAP;
    // dump for softmax/needgather (coalesced) + needlist marking
    if (t < SUB) {
        int n = g * SUB + t;
        if (n < NN) {
            deg[n] = lhist[t];
            off[n] = base + lstart[t];
            if (maskb[n] != 0) {
                // masked node: layer-2 output read at n (pbase/vbase) and at
                // its in-edge sources (pv). Dedup via needb.
                if (atomicExch(needb + n, 1) == 0) {
                    int ix = atomicAdd(ncount, 1);
                    if (ix < NCAP) needlist[ix] = n;
                }
                int s0 = lstart[t], dgn = lhist[t];
                for (int i2 = 0; i2 < dgn; ++i2) {
                    int s = ent_s(sE[s0 + i2]);
                    if (atomicExch(needb + s, 1) == 0) {
                        int ix = atomicAdd(ncount, 1);
                        if (ix < NCAP) needlist[ix] = s;
                    }
                }
            }
        }
    }
    for (int i = t; i < cnt; i += 1024) {
        unsigned pos = (unsigned)(base + i);
        if (pos < (unsigned)CSRN) csr4[pos] = sE[i];
    }
    // ----------------------------- gather phase -----------------------------
    int q = t & 3;
    int f0 = q * 8;
    int l = t >> 2;                 // local node 0..255
    int n = g * SUB + l;
    if (n >= NN) return;
    int st = lstart[l];
    int dg = lhist[l];
    if (st < 0) st = 0;
    if (st > BCAP) st = BCAP;
    if (dg < 0) dg = 0;
    if (dg > BCAP - st) dg = BCAP - st;
    float acc[8] = {0.f, 0.f, 0.f, 0.f, 0.f, 0.f, 0.f, 0.f};
    int i = 0;
    for (; i + 1 < dg; i += 2) {
        unsigned e0 = sE[st + i];
        unsigned e1 = sE[st + i + 1];
        float w0 = ent_w(e0), w1 = ent_w(e1);
        float4 r0 = *(const float4*)(proj1 + (size_t)ent_s(e0) * 32 + f0);
        float4 r1 = *(const float4*)(proj1 + (size_t)ent_s(e1) * 32 + f0);
        const __half2* h0 = (const __half2*)&r0;
        const __half2* h1p = (const __half2*)&r1;
#pragma unroll
        for (int u = 0; u < 4; ++u) {
            float2 a = __half22float2(h0[u]);
            float2 b = __half22float2(h1p[u]);
            acc[2 * u] = fmaf(w0, a.x, acc[2 * u]);
            acc[2 * u + 1] = fmaf(w0, a.y, acc[2 * u + 1]);
            acc[2 * u] = fmaf(w1, b.x, acc[2 * u]);
            acc[2 * u + 1] = fmaf(w1, b.y, acc[2 * u + 1]);
        }
    }
    if (i < dg) {
        unsigned e0 = sE[st + i];
        float w0 = ent_w(e0);
        float4 r0 = *(const float4*)(proj1 + (size_t)ent_s(e0) * 32 + f0);
        const __half2* h0 = (const __half2*)&r0;
#pragma unroll
        for (int u = 0; u < 4; ++u) {
            float2 a = __half22float2(h0[u]);
            acc[2 * u] = fmaf(w0, a.x, acc[2 * u]);
            acc[2 * u + 1] = fmaf(w0, a.y, acc[2 * u + 1]);
        }
    }
    float4 rr = *(const float4*)(root1 + (size_t)n * 32 + f0);
    const __half2* rp = (const __half2*)&rr;
    float h[8];
#pragma unroll
    for (int u = 0; u < 4; ++u) {
        float2 f2 = __half22float2(rp[u]);
        h[2 * u] = fmaxf(acc[2 * u] + f2.x, 0.f);
        h[2 * u + 1] = fmaxf(acc[2 * u + 1] + f2.y, 0.f);
    }
    *(float4*)(h1 + (size_t)n * 32 + f0) = pack8(h);
}

// ---------------------------------------------------------------------------
// mm2: proj2 = fp16(h1@Wh_rel), root2 = fp16(h1@Wh_root + bh). K=32.
// (Stays full-graph: the needed nodes' gathers read proj2 at arbitrary srcs.)
// ---------------------------------------------------------------------------
__global__ void __launch_bounds__(256) mm2_k(
    const __half* __restrict__ h1, const float* __restrict__ Wrel,
    const float* __restrict__ Wroot, const float* __restrict__ bh,
    __half* __restrict__ proj2, __half* __restrict__ root2)
{
    __shared__ float sX[128 * 33];
    __shared__ float sW[32 * 68];
    int t = threadIdx.x;
    for (int i = t; i < 32 * 32; i += 256) {
        int k = i >> 5, j = i & 31;
        sW[k * 68 + j] = Wrel[i];
        sW[k * 68 + 32 + j] = Wroot[i];
    }
    int base = blockIdx.x * 128;
    for (int i = t; i < 512; i += 256) {
        int node = i >> 2;
        int hs = (i & 3) * 8;
        int n = base + node;
        if (n >= NN) n = NN - 1;
        float4 v = *(const float4*)(h1 + (size_t)n * 32 + hs);
        const __half2* hp = (const __half2*)&v;
        float* p = sX + node * 33 + hs;
#pragma unroll
        for (int u = 0; u < 4; ++u) {
            float2 f2 = __half22float2(hp[u]);
            p[2 * u] = f2.x;
            p[2 * u + 1] = f2.y;
        }
    }
    __syncthreads();
    int cg = t & 7;
    int ng = t >> 3;
    int c0 = 8 * cg;
    float acc[4][8] = {};
    for (int k = 0; k < 32; ++k) {
        float xv0 = sX[(4 * ng + 0) * 33 + k];
        float xv1 = sX[(4 * ng + 1) * 33 + k];
        float xv2 = sX[(4 * ng + 2) * 33 + k];
        float xv3 = sX[(4 * ng + 3) * 33 + k];
        float4 w0 = *(const float4*)(sW + k * 68 + c0);
        float4 w1 = *(const float4*)(sW + k * 68 + c0 + 4);
        const float* wp = (const float*)&w0;
#pragma unroll
        for (int j = 0; j < 4; ++j) {
            float w = wp[j];
            acc[0][j] = fmaf(xv0, w, acc[0][j]);
            acc[1][j] = fmaf(xv1, w, acc[1][j]);
            acc[2][j] = fmaf(xv2, w, acc[2][j]);
            acc[3][j] = fmaf(xv3, w, acc[3][j]);
        }
        const float* wq = (const float*)&w1;
#pragma unroll
        for (int j = 0; j < 4; ++j) {
            float w = wq[j];
            acc[0][4 + j] = fmaf(xv0, w, acc[0][4 + j]);
            acc[1][4 + j] = fmaf(xv1, w, acc[1][4 + j]);
            acc[2][4 + j] = fmaf(xv2, w, acc[2][4 + j]);
            acc[3][4 + j] = fmaf(xv3, w, acc[3][4 + j]);
        }
    }
#pragma unroll
    for (int r = 0; r < 4; ++r) {
        int n = base + 4 * ng + r;
        if (n >= NN) break;
        if (cg < 4) {
            *(float4*)(proj2 + (size_t)n * 32 + c0) = pack8(acc[r]);
        } else {
            int c = c0 - 32;
            float v[8];
#pragma unroll
            for (int j = 0; j < 8; ++j) v[j] = acc[r][j] + bh[c + j];
            *(float4*)(root2 + (size_t)n * 32 + c) = pack8(v);
        }
    }
}

// ---------------------------------------------------------------------------
// need_gather: agg2's 4-deep gather + head-dot epilogue, but ONLY over the
// needlist (~1.4K nodes) instead of all 100K. Identical csr order and fmaf
// chain -> bit-identical pv/pbase/vbase at every node the softmax reads.
// ---------------------------------------------------------------------------
__global__ void __launch_bounds__(256) need_gather_k(
    const __half* __restrict__ proj2, const __half* __restrict__ root2,
    const float* __restrict__ Wp_rel, const float* __restrict__ Wp_root,
    const float* __restrict__ bp, const float* __restrict__ Wv_rel,
    const float* __restrict__ Wv_root, const float* __restrict__ bv,
    const unsigned* __restrict__ csr4, const int* __restrict__ off,
    const int* __restrict__ deg, const int* __restrict__ needlist,
    const int* __restrict__ ncount, float2* __restrict__ pv,
    float* __restrict__ pbase, float* __restrict__ vbase)
{
    __shared__ float sHead[4 * 32];
    if (threadIdx.x < 32) {
        sHead[threadIdx.x] = Wp_rel[threadIdx.x];
        sHead[32 + threadIdx.x] = Wp_root[threadIdx.x];
        sHead[64 + threadIdx.x] = Wv_rel[threadIdx.x];
        sHead[96 + threadIdx.x] = Wv_root[threadIdx.x];
    }
    __syncthreads();
    int t = threadIdx.x;
    int q = t & 3;
    int f0 = q * 8;
    int m = ncount[0];
    if (m > NCAP) m = NCAP;
    int idx = blockIdx.x * 64 + (t >> 2);
    if (idx >= m) return;
    int n = needlist[idx];
    if ((unsigned)n >= (unsigned)NN) n = 0;
    int st = off[n];
    int dg = deg[n];
    if (st < 0) st = 0;
    if (st > CSRN) st = CSRN;
    if (dg < 0) dg = 0;
    if (dg > CSRN - st) dg = CSRN - st;
    float acc[8] = {0.f, 0.f, 0.f, 0.f, 0.f, 0.f, 0.f, 0.f};
    int i = 0;
    for (; i + 3 < dg; i += 4) {
        unsigned e0 = csr4[st + i];
        unsigned e1 = csr4[st + i + 1];
        unsigned e2 = csr4[st + i + 2];
        unsigned e3 = csr4[st + i + 3];
        float4 r0 = *(const float4*)(proj2 + (size_t)ent_s(e0) * 32 + f0);
        float4 r1 = *(const float4*)(proj2 + (size_t)ent_s(e1) * 32 + f0);
        float4 r2 = *(const float4*)(proj2 + (size_t)ent_s(e2) * 32 + f0);
        float4 r3 = *(const float4*)(proj2 + (size_t)ent_s(e3) * 32 + f0);
        float w0 = ent_w(e0), w1 = ent_w(e1), w2 = ent_w(e2), w3 = ent_w(e3);
        const __half2* h0 = (const __half2*)&r0;
        const __half2* h1p = (const __half2*)&r1;
        const __half2* h2p = (const __half2*)&r2;
        const __half2* h3p = (const __half2*)&r3;
#pragma unroll
        for (int u = 0; u < 4; ++u) {
            float2 a = __half22float2(h0[u]);
            float2 b = __half22float2(h1p[u]);
            float2 c = __half22float2(h2p[u]);
            float2 d = __half22float2(h3p[u]);
            acc[2 * u]     = fmaf(w0, a.x, acc[2 * u]);
            acc[2 * u + 1] = fmaf(w0, a.y, acc[2 * u + 1]);
            acc[2 * u]     = fmaf(w1, b.x, acc[2 * u]);
            acc[2 * u + 1] = fmaf(w1, b.y, acc[2 * u + 1]);
            acc[2 * u]     = fmaf(w2, c.x, acc[2 * u]);
            acc[2 * u + 1] = fmaf(w2, c.y, acc[2 * u + 1]);
            acc[2 * u]     = fmaf(w3, d.x, acc[2 * u]);
            acc[2 * u + 1] = fmaf(w3, d.y, acc[2 * u + 1]);
        }
    }
    for (; i < dg; ++i) {
        unsigned e0 = csr4[st + i];
        float w0 = ent_w(e0);
        float4 r0 = *(const float4*)(proj2 + (size_t)ent_s(e0) * 32 + f0);
        const __half2* h0 = (const __half2*)&r0;
#pragma unroll
        for (int u = 0; u < 4; ++u) {
            float2 a = __half22float2(h0[u]);
            acc[2 * u] = fmaf(w0, a.x, acc[2 * u]);
            acc[2 * u + 1] = fmaf(w0, a.y, acc[2 * u + 1]);
        }
    }
    float4 rr = *(const float4*)(root2 + (size_t)n * 32 + f0);
    const __half2* rp = (const __half2*)&rr;
    float h[8];
#pragma unroll
    for (int u = 0; u < 4; ++u) {
        float2 f2 = __half22float2(rp[u]);
        h[2 * u] = fmaxf(acc[2 * u] + f2.x, 0.f);
        h[2 * u + 1] = fmaxf(acc[2 * u + 1] + f2.y, 0.f);
    }
    float prv = 0.f, pov = 0.f, vrv = 0.f, vov = 0.f;
#pragma unroll
    for (int j = 0; j < 8; ++j) {
        prv = fmaf(h[j], sHead[f0 + j], prv);
        pov = fmaf(h[j], sHead[32 + f0 + j], pov);
        vrv = fmaf(h[j], sHead[64 + f0 + j], vrv);
        vov = fmaf(h[j], sHead[96 + f0 + j], vov);
    }
#pragma unroll
    for (int mm = 1; mm <= 2; mm <<= 1) {
        prv += __shfl_xor(prv, mm, 64);
        pov += __shfl_xor(pov, mm, 64);
        vrv += __shfl_xor(vrv, mm, 64);
        vov += __shfl_xor(vov, mm, 64);
    }
    if (q == 0) {
        pv[n] = make_float2(prv, vrv);
        pbase[n] = pov + bp[0];
        vbase[n] = vov + bv[0];
    }
}

// ---------------------------------------------------------------------------
// Single-block masked softmax; 4 lanes per node cut the serial pv-gather
// chain 4x (2-step shfl reduce). Sparse writes (d_out pre-zeroed).
// ---------------------------------------------------------------------------
__global__ void __launch_bounds__(256) masked_softmax_k(
    const int* __restrict__ mlist, const int* __restrict__ mcount,
    const unsigned* __restrict__ csr4, const int* __restrict__ off,
    const int* __restrict__ deg, const float2* __restrict__ pv,
    const float* __restrict__ pbase, const float* __restrict__ vbase,
    float* __restrict__ out_p, float* __restrict__ out_v)
{
    __shared__ float sPm[MCAP];
    __shared__ float sV[MCAP];
    __shared__ int sN[MCAP];
    __shared__ float sMx, sSum;
    __shared__ float sred[4];
    int m = mcount[0];
    if (m > MCAP) m = MCAP;
    if (m < 0) m = 0;
    int lane4 = threadIdx.x & 3;
    for (int idx = threadIdx.x >> 2; idx < m; idx += 64) {
        int n = mlist[idx];
        if ((unsigned)n >= (unsigned)NN) n = 0;
        int st = off[n];
        int dg = deg[n];
        if (st < 0) st = 0;
        if (st > CSRN) st = CSRN;
        if (dg < 0) dg = 0;
        if (dg > CSRN - st) dg = CSRN - st;
        float pa = 0.f, va = 0.f;
        for (int i = lane4; i < dg; i += 4) {
            unsigned ent = csr4[st + i];
            int s = ent_s(ent);
            float w = ent_w(ent);
            float2 tv = pv[s];
            pa = fmaf(tv.x, w, pa);
            va = fmaf(tv.y, w, va);
        }
        pa += __shfl_xor(pa, 1, 64);
        pa += __shfl_xor(pa, 2, 64);
        va += __shfl_xor(va, 1, 64);
        va += __shfl_xor(va, 2, 64);
        if (lane4 == 0) {
            sN[idx] = n;
            float p = pa + pbase[n];
            sPm[idx] = (p == 0.f) ? -INFINITY : p;
            sV[idx] = va + vbase[n];
        }
    }
    __syncthreads();
    float mx = -INFINITY;
    for (int i = threadIdx.x; i < m; i += 256) mx = fmaxf(mx, sPm[i]);
#pragma unroll
    for (int k = 32; k; k >>= 1) mx = fmaxf(mx, __shfl_xor(mx, k, 64));
    if ((threadIdx.x & 63) == 0) sred[threadIdx.x >> 6] = mx;
    __syncthreads();
    if (threadIdx.x == 0)
        sMx = fmaxf(fmaxf(sred[0], sred[1]), fmaxf(sred[2], sred[3]));
    __syncthreads();
    float sum = 0.f;
    for (int i = threadIdx.x; i < m; i += 256) {
        float x = sPm[i];
        sum += (x == -INFINITY) ? 0.f : expf(x - sMx);
    }
#pragma unroll
    for (int k = 32; k; k >>= 1) sum += __shfl_xor(sum, k, 64);
    if ((threadIdx.x & 63) == 0) sred[threadIdx.x >> 6] = sum;
    __syncthreads();
    if (threadIdx.x == 0) sSum = sred[0] + sred[1] + sred[2] + sred[3];
    __syncthreads();
    for (int idx = threadIdx.x; idx < m; idx += 256) {
        int n = sN[idx];
        float x = sPm[idx];
        out_p[n] = (x == -INFINITY) ? 0.f : expf(x - sMx) / sSum;
        out_v[n] = sV[idx];
    }
}

// ---------------------------------------------------------------------------
extern "C" void kernel_launch(void* const* d_in, const int* in_sizes, int n_in,
                              void* d_out, int out_size, void* d_ws,
                              size_t ws_size, hipStream_t stream)
{
    const float* x        = (const float*)d_in[0];
    const int*   ei       = (const int*)d_in[1];
    const float* ew       = (const float*)d_in[2];
    const int*   cur      = (const int*)d_in[3];
    const float* Win_rel  = (const float*)d_in[4];
    const float* bin_rel  = (const float*)d_in[5];
    const float* Win_root = (const float*)d_in[6];
    const float* Wh_rel   = (const float*)d_in[7];
    const float* bh_rel   = (const float*)d_in[8];
    const float* Wh_root  = (const float*)d_in[9];
    const float* Wp_rel   = (const float*)d_in[10];
    const float* bp       = (const float*)d_in[11];
    const float* Wp_root  = (const float*)d_in[12];
    const float* Wv_rel   = (const float*)d_in[13];
    const float* bv       = (const float*)d_in[14];
    const float* Wv_root  = (const float*)d_in[15];

    const int* srcA = ei;
    const int* dstA = ei + NE;

    // Workspace (~54 MB):
    //   csr4 (8.13MB) | deg | off |
    //   [zeroed: maskb | mcount | bcnt | needb | ncnt] | mlist | needlist |
    //   proj1 root1 h1 proj2 root2 (32MB) | pv/pbase/vbase |
    //   bucket_x (8.13MB) | bucket_d (2.03MB)
    char* w8 = (char*)d_ws;
    unsigned* csr4 = (unsigned*)w8;          // CSRN u32
    int* deg    = (int*)(csr4 + CSRN);       // NN
    int* off    = deg + NN;                  // NN
    int* maskb  = off + NN;                  // NN  }  zeroed
    int* mcount = maskb + NN;                // 8   }
    int* bcnt   = mcount + 8;                // 400 }
    int* needb  = bcnt + 400;                // NN  }
    int* ncnt   = needb + NN;                // 8   } (2*NN+416 ints)
    int* mlist  = ncnt + 8;                  // MCAP
    int* needlist = mlist + MCAP;            // NCAP
    __half* proj1 = (__half*)(needlist + NCAP);
    __half* root1 = proj1 + NW;
    __half* h1    = root1 + NW;
    __half* proj2 = h1 + NW;
    __half* root2 = proj2 + NW;
    float2* pv    = (float2*)(root2 + NW);   // 800 KB
    float* pbase  = (float*)(pv + NN);       // 400 KB
    float* vbase  = pbase + NN;              // 400 KB
    unsigned* bucket_x = (unsigned*)(vbase + NN);                // CSRN u32
    unsigned char* bucket_d = (unsigned char*)(bucket_x + CSRN); // CSRN u8

    float* out_p = (float*)d_out;
    float* out_v = out_p + NN;

    const int NB_MM    = (NN + 127) / 128;   // 782
    const int NB_FUSED = NCH + NB_MM;        // 978
    const int NB_NEED  = NCAP / 64;          // 128

    // zero: maskb + mcount + bcnt + needb + ncnt, and d_out
    hipMemsetAsync(maskb, 0, ((size_t)2 * NN + 416) * sizeof(int), stream);
    hipMemsetAsync(d_out, 0, 2 * (size_t)NN * sizeof(float), stream);

    // --- fused CSR-bucket build (split planes, atomic reservation) + mm1 ---
    fused_build_mm1_k<<<NB_FUSED, 512, 0, stream>>>(
        srcA, dstA, ew, cur, maskb, mcount, mlist, bcnt, bucket_x, bucket_d,
        x, Win_rel, Win_root, bin_rel, proj1, root1);
    // --- per-sub-slice sort (in-LDS) + agg1 fused + needlist marking ---
    sortagg1_k<<<NSUB, 1024, 0, stream>>>(bucket_x, bucket_d, bcnt, maskb,
                                          needb, ncnt, needlist,
                                          proj1, root1, csr4, deg, off, h1);
    // --- layer chain ---
    mm2_k<<<NB_MM, 256, 0, stream>>>(h1, Wh_rel, Wh_root, bh_rel, proj2, root2);
    // --- layer-2 gather ONLY at nodes whose output is read (~1.4K) ---
    need_gather_k<<<NB_NEED, 256, 0, stream>>>(
        proj2, root2, Wp_rel, Wp_root, bp, Wv_rel, Wv_root, bv,
        csr4, off, deg, needlist, ncnt, pv, pbase, vbase);
    // --- masked softmax (sparse outputs) ---
    masked_softmax_k<<<1, 256, 0, stream>>>(mlist, mcount, csr4, off, deg, pv,
                                            pbase, vbase, out_p, out_v);
}